// Round 12
// baseline (739.914 us; speedup 1.0000x reference)
//
#include <hip/hip_runtime.h>
#include <math.h>

typedef _Float16 f16;
typedef _Float16 f16x4 __attribute__((ext_vector_type(4)));
typedef _Float16 f16x8 __attribute__((ext_vector_type(8)));
typedef float f32x4 __attribute__((ext_vector_type(4)));

#define NB 16      // batch
#define NT 16      // time steps
#define NH 64
#define NW 64
#define NF 64      // features
#define NG 256     // 4*F
#define HWF ((size_t)NH * NW * NF)          // 262144
#define OUT_BSTRIDE ((size_t)NT * HWF)      // d_out batch stride
#define RS2 8448                            // LDS row stride = 66 * 128 B (x-padded)
#define ZS 258                              // zbuf row stride in floats
#define WSTEP ((size_t)18432)               // per-step wf2 size in f16x8 chunks (hi-only)

#define MFMA(a, b, c) __builtin_amdgcn_mfma_f32_16x16x32_f16((a), (b), (c), 0, 0, 0)

__device__ __forceinline__ void gload_lds16(const void* g, void* l) {
    __builtin_amdgcn_global_load_lds(
        (const __attribute__((address_space(1))) unsigned int*)(g),
        (__attribute__((address_space(3))) unsigned int*)(l), 16, 0, 0);
}

__device__ __forceinline__ float hsig(float x) {
    return fminf(fmaxf(0.2f * x + 0.5f, 0.0f), 1.0f);
}

// fast tanh via v_exp_f32 (rounds 8-11 verified absmax-neutral)
__device__ __forceinline__ float ftanh(float x) {
    float t = __builtin_amdgcn_exp2f(x * 2.885390081777927f);
    return 1.0f - 2.0f * __builtin_amdgcn_rcpf(t + 1.0f);
}

// ---- prologue 1: fuse W+U -> f16 (hi only), lane-ordered chunks:
// chunk (f16x8 units): (tap*2+kk)*1024 + (cout>>4)*64 + lane
// lane = lg*16 + (cout&15) holds cin = kk*32 + lg*8 .. +7.
__global__ void fuse_w_hi(const float* __restrict__ k, const float* __restrict__ rk,
                          f16* __restrict__ wf2) {
    int idx = blockIdx.x * 256 + threadIdx.x;      // over 16*9*256*8 = 294912
    if (idx >= NT * 9 * NG * 8) return;
    int g8   = idx & 7;
    int cout = (idx >> 3) & 255;
    int tt   = idx >> 11;          // t*9 + tap
    int tap  = tt % 9;
    int t    = tt / 9;
    int kk = g8 >> 2, lg = g8 & 3;

    const float* ks = k  + (size_t)tt * NF * NG + cout;
    const float* rs = rk + (size_t)tt * NF * NG + cout;

    f16 hi8[8];
#pragma unroll
    for (int j = 0; j < 8; ++j) {
        int cin = kk * 32 + lg * 8 + j;
        hi8[j] = (f16)(ks[(size_t)cin * NG] + rs[(size_t)cin * NG]);
    }
    const int lane = lg * 16 + (cout & 15);
    size_t chunk = (size_t)t * WSTEP + (size_t)(tap * 2 + kk) * 1024 +
                   (size_t)(cout >> 4) * 64 + lane;
    *(f16x8*)&wf2[chunk * 8] = *(f16x8*)hi8;
}

// ---- prologue 2: f32 -> f16 vectorized converter (h0 and c0)
__global__ void f32_to_f16(const float* __restrict__ src, f16* __restrict__ dst, int n4) {
    int i = blockIdx.x * 256 + threadIdx.x;
    if (i >= n4) return;
    float4 v = ((const float4*)src)[i];
    f16x4 o = { (f16)v.x, (f16)v.y, (f16)v.z, (f16)v.w };
    *(f16x4*)&dst[(size_t)i * 4] = o;
}

// ---- one ConvLSTM step: 256 threads = 4 waves (1m x 4n), block tile
// M=64 (one image row) x N=256 couts. 4 blocks/CU (LDS 33KB, VGPR<=128) give
// 4-way phase skew. 1D grid with batch-sticky XCD swizzle: XCD = bb>>1, so
// each XCD keeps its 2 batches' h2/c in local L2 across all 16 steps.
__global__ void __launch_bounds__(256, 4)
convlstm_mfma_step(const f16* __restrict__ h2in, f16* __restrict__ h2out,
                   f16* __restrict__ cbuf,        // f16 cell state (in-place)
                   float* __restrict__ hout,        // d_out + t*HWF
                   const f16* __restrict__ wt,      // hi-only lane-ordered chunks
                   const float* __restrict__ bias)  // [256] for this t
{
    __shared__ __align__(16) unsigned char lds[33024];   // max(3*RS2, 32*ZS*4)

    const int tid  = threadIdx.x;
    const int w    = tid >> 6;     // wave 0..3 = n-slice
    const int lane = tid & 63;

    // batch-sticky XCD decode: id = (iy + 64*bhalf)*8 + xcd ; bb = xcd*2 + bhalf
    const int id = blockIdx.x;
    const int bb = ((id & 7) << 1) + ((id >> 9) & 1);
    const int y0 = (id >> 3) & 63;

    // zero pad columns tx=0 and tx=65 for the 3 staged rows
    if (tid < 48) {
        int row = tid >> 4, side = (tid >> 3) & 1, j = tid & 7;
        *(f16x8*)&lds[row * RS2 + side * (65 * 128) + j * 16] = (f16x8)(_Float16)0.0f;
    }

    // stage rows y0-1 .. y0+1 (one per wave 0..2); pre-swizzled global source
    if (w < 3) {
        const int gy = y0 - 1 + w;
        const unsigned dbase = w * RS2 + 128;            // wave-uniform
        if (gy >= 0 && gy < NH) {
            const unsigned char* gsrc = (const unsigned char*)h2in +
                ((((size_t)bb * NH + gy) * NW) << 7);    // 128 B per (y,x)
#pragma unroll
            for (int i = 0; i < 8; ++i) {
                const int xrel = i * 8 + (lane >> 3);
                const unsigned src = ((unsigned)xrel << 7) +
                    ((unsigned)((lane & 7) ^ ((xrel + 1) & 7)) << 4);
                gload_lds16(gsrc + src, (void*)&lds[dbase + i * 1024]);
            }
        } else {
            const f16x8 zf = (f16x8)(_Float16)0.0f;
#pragma unroll
            for (int i = 0; i < 8; ++i)
                *(f16x8*)&lds[dbase + i * 1024 + lane * 16] = zf;
        }
    }
    __syncthreads();

    // ---------- K loop: 9 taps x 2 cin-halves, fully unrolled, 1-term f16
    const int lm = lane & 15;
    const int lg = lane >> 4;

    f32x4 acc[4][4];
#pragma unroll
    for (int mf = 0; mf < 4; ++mf)
#pragma unroll
        for (int nf = 0; nf < 4; ++nf) acc[mf][nf] = (f32x4)0.0f;

    // per-lane swizzled A offsets: tx = lm + d, granule g = kk*4+lg, slot = g ^ (tx&7)
    unsigned av[3][2];
#pragma unroll
    for (int d = 0; d < 3; ++d)
#pragma unroll
        for (int kk = 0; kk < 2; ++kk) {
            const int tx = lm + d;
            av[d][kk] = (unsigned)(tx * 128 +
                        (((kk * 4 + lg) ^ (tx & 7)) << 4));
        }

    const f16x8* wb = (const f16x8*)wt + (size_t)(w * 4) * 64 + lane;

    f16x8 bh[4];
#pragma unroll
    for (int it = 0; it < 18; ++it) {
        const int tap = it >> 1, kk = it & 1;
#pragma unroll
        for (int nf = 0; nf < 4; ++nf)
            bh[nf] = wb[(size_t)it * 1024 + nf * 64];
        const int ty = tap / 3;
        const int d  = tap - ty * 3;
        const unsigned abase = (unsigned)(ty * RS2) + av[d][kk];
        __builtin_amdgcn_s_setprio(1);
#pragma unroll
        for (int mf = 0; mf < 4; ++mf) {
            const f16x8 ah = *(const f16x8*)&lds[abase + mf * 2048];
#pragma unroll
            for (int nf = 0; nf < 4; ++nf)
                acc[mf][nf] = MFMA(ah, bh[nf], acc[mf][nf]);
        }
        __builtin_amdgcn_s_setprio(0);
    }

    __syncthreads();

    // ---------- epilogue: two x-passes of 32 columns (zbuf 33KB fits tile LDS)
    float* zbuf = (float*)lds;
    const int f = tid & 63;
    const float bi = bias[f], bfv = bias[64 + f], bcv = bias[128 + f], bov = bias[192 + f];

#pragma unroll 1
    for (int xp = 0; xp < 2; ++xp) {
#pragma unroll
        for (int m2 = 0; m2 < 2; ++m2) {
            const int mf = xp * 2 + m2;
#pragma unroll
            for (int nf = 0; nf < 4; ++nf)
#pragma unroll
                for (int j = 0; j < 4; ++j)
                    zbuf[(m2 * 16 + lg * 4 + j) * ZS + w * 64 + nf * 16 + lm] =
                        acc[mf][nf][j];
        }
        __syncthreads();
#pragma unroll 1
        for (int k2 = 0; k2 < 8; ++k2) {
            const int xl = (tid >> 6) + k2 * 4;          // 0..31 (wave-uniform)
            const int x  = xp * 32 + xl;
            const float* zz = zbuf + xl * ZS;
            float zi  = zz[f]       + bi;
            float zfv = zz[64 + f]  + bfv;
            float zc  = zz[128 + f] + bcv;
            float zo  = zz[192 + f] + bov;
            size_t goff = (((size_t)bb * NH + y0) * NW + x) * NF + f;
            float cp = (float)cbuf[goff];
            float ig = hsig(zi), fg = hsig(zfv), og = hsig(zo);
            float cn = fg * cp + ig * ftanh(zc);
            cbuf[goff] = (f16)cn;
            float hn = og * ftanh(cn);
            hout[(size_t)bb * OUT_BSTRIDE + (((size_t)y0 * NW + x) * NF + f)] = hn;
            h2out[goff] = (f16)hn;
        }
        __syncthreads();
    }
}

extern "C" void kernel_launch(void* const* d_in, const int* in_sizes, int n_in,
                              void* d_out, int out_size, void* d_ws, size_t ws_size,
                              hipStream_t stream) {
    const float* h0    = (const float*)d_in[1];
    const float* c0    = (const float*)d_in[2];
    const float* kern  = (const float*)d_in[3];
    const float* rkern = (const float*)d_in[4];
    const float* bias  = (const float*)d_in[5];
    float* out = (float*)d_out;

    f16* wf2   = (f16*)d_ws;                                  // 4.7 MB (hi only)
    f16* h2a   = wf2 + (size_t)NT * WSTEP * 8;                // 8.4 MB
    f16* h2b   = h2a + (size_t)NB * HWF;                      // 8.4 MB
    f16* cbuf  = h2b + (size_t)NB * HWF;                      // 8.4 MB (f16 c state)

    const int n4 = (int)(NB * HWF / 4);                       // 1,048,576
    fuse_w_hi<<<(NT * 9 * NG * 8 + 255) / 256, 256, 0, stream>>>(kern, rkern, wf2);
    f32_to_f16<<<(n4 + 255) / 256, 256, 0, stream>>>(h0, h2a, n4);
    f32_to_f16<<<(n4 + 255) / 256, 256, 0, stream>>>(c0, cbuf, n4);

    for (int t = 0; t < NT; ++t) {
        const f16* hin = (t & 1) ? h2b : h2a;
        f16* hnx       = (t & 1) ? h2a : h2b;
        convlstm_mfma_step<<<dim3(NH * NB), 256, 0, stream>>>(
            hin, hnx, cbuf,
            out + (size_t)t * HWF,
            wf2 + (size_t)t * WSTEP * 8,
            bias + t * NG);
    }
}

// Round 13
// 443.988 us; speedup vs baseline: 1.6665x; 1.6665x over previous
//
#include <hip/hip_runtime.h>
#include <math.h>

typedef _Float16 f16;
typedef _Float16 f16x4 __attribute__((ext_vector_type(4)));
typedef _Float16 f16x8 __attribute__((ext_vector_type(8)));
typedef float f32x4 __attribute__((ext_vector_type(4)));

#define NB 16      // batch
#define NT 16      // time steps
#define NH 64
#define NW 64
#define NF 64      // features
#define NG 256     // 4*F
#define HWF ((size_t)NH * NW * NF)          // 262144
#define OUT_BSTRIDE ((size_t)NT * HWF)      // d_out batch stride
#define RS2 8448                            // LDS row stride = 66 * 128 B (x-padded)
#define ZS 258                              // zbuf row stride in floats
#define WSTEP ((size_t)18432)               // per-step wf2 size in f16x8 chunks (hi-only)

#define MFMA(a, b, c) __builtin_amdgcn_mfma_f32_16x16x32_f16((a), (b), (c), 0, 0, 0)

__device__ __forceinline__ void gload_lds16(const void* g, void* l) {
    __builtin_amdgcn_global_load_lds(
        (const __attribute__((address_space(1))) unsigned int*)(g),
        (__attribute__((address_space(3))) unsigned int*)(l), 16, 0, 0);
}

__device__ __forceinline__ float hsig(float x) {
    return fminf(fmaxf(0.2f * x + 0.5f, 0.0f), 1.0f);
}

// fast tanh via v_exp_f32 (rounds 8-11 verified absmax-neutral)
__device__ __forceinline__ float ftanh(float x) {
    float t = __builtin_amdgcn_exp2f(x * 2.885390081777927f);
    return 1.0f - 2.0f * __builtin_amdgcn_rcpf(t + 1.0f);
}

// ---- prologue 1: fuse W+U -> f16 (hi only), lane-ordered chunks:
// chunk (f16x8 units): (tap*2+kk)*1024 + (cout>>4)*64 + lane
// lane = lg*16 + (cout&15) holds cin = kk*32 + lg*8 .. +7.
__global__ void fuse_w_hi(const float* __restrict__ k, const float* __restrict__ rk,
                          f16* __restrict__ wf2) {
    int idx = blockIdx.x * 256 + threadIdx.x;      // over 16*9*256*8 = 294912
    if (idx >= NT * 9 * NG * 8) return;
    int g8   = idx & 7;
    int cout = (idx >> 3) & 255;
    int tt   = idx >> 11;          // t*9 + tap
    int tap  = tt % 9;
    int t    = tt / 9;
    int kk = g8 >> 2, lg = g8 & 3;

    const float* ks = k  + (size_t)tt * NF * NG + cout;
    const float* rs = rk + (size_t)tt * NF * NG + cout;

    f16 hi8[8];
#pragma unroll
    for (int j = 0; j < 8; ++j) {
        int cin = kk * 32 + lg * 8 + j;
        hi8[j] = (f16)(ks[(size_t)cin * NG] + rs[(size_t)cin * NG]);
    }
    const int lane = lg * 16 + (cout & 15);
    size_t chunk = (size_t)t * WSTEP + (size_t)(tap * 2 + kk) * 1024 +
                   (size_t)(cout >> 4) * 64 + lane;
    *(f16x8*)&wf2[chunk * 8] = *(f16x8*)hi8;
}

// ---- prologue 2: f32 -> f16 vectorized converter (h0 and c0)
__global__ void f32_to_f16(const float* __restrict__ src, f16* __restrict__ dst, int n4) {
    int i = blockIdx.x * 256 + threadIdx.x;
    if (i >= n4) return;
    float4 v = ((const float4*)src)[i];
    f16x4 o = { (f16)v.x, (f16)v.y, (f16)v.z, (f16)v.w };
    *(f16x4*)&dst[(size_t)i * 4] = o;
}

// ---- one ConvLSTM step: round-11 structure (512 thr, 2 rows x 256 couts,
// 2 blocks/CU). ONLY change vs round 11: 1D grid + batch-sticky XCD decode
// (xcd = id&7 under round-robin dispatch; bb = xcd*2 + bhalf) so each XCD
// keeps its 2 batches' h2/c in its private L2 across all 16 steps.
__global__ void __launch_bounds__(512, 4)
convlstm_mfma_step(const f16* __restrict__ h2in, f16* __restrict__ h2out,
                   f16* __restrict__ cbuf,        // f16 cell state (in-place)
                   float* __restrict__ hout,        // d_out + t*HWF
                   const f16* __restrict__ wt,      // hi-only lane-ordered chunks
                   const float* __restrict__ bias)  // [256] for this t
{
    __shared__ __align__(16) unsigned char lds[67584];

    const int tid  = threadIdx.x;
    const int w    = tid >> 6;
    const int lane = tid & 63;

    // batch-sticky XCD decode: id = xcd + 8*iy + 256*bhalf
    const int id    = blockIdx.x;
    const int bb    = ((id & 7) << 1) + ((id >> 8) & 1);
    const int y0    = ((id >> 3) & 31) * 2;

    // zero the pad columns tx=0 and tx=65 (4 rows x 2 x 128B)
    if (tid < 64) {
        int row = tid >> 4, side = (tid >> 3) & 1, j = tid & 7;
        *(f16x8*)&lds[row * RS2 + side * (65 * 128) + j * 16] = (f16x8)(_Float16)0.0f;
    }

    // stage rows y0-1 .. y0+2 (f16, 128B per (y,x)); pre-swizzled global source
    {
        const int r    = w >> 1;               // tile row 0..3
        const int gy   = y0 - 1 + r;
        const int half = w & 1;
        const unsigned dbase = r * RS2 + 128 + half * 4096;  // wave-uniform
        if (gy >= 0 && gy < NH) {
            const unsigned char* gsrc = (const unsigned char*)h2in +
                ((((size_t)bb * NH + gy) * NW) << 7);        // 128 B per (y,x)
#pragma unroll
            for (int i = 0; i < 4; ++i) {
                const int xrel = half * 32 + i * 8 + (lane >> 3);
                const unsigned src = ((unsigned)xrel << 7) +
                    ((unsigned)((lane & 7) ^ ((xrel + 1) & 7)) << 4);
                gload_lds16(gsrc + src, (void*)&lds[dbase + i * 1024]);
            }
        } else {
            const f16x8 zf = (f16x8)(_Float16)0.0f;
#pragma unroll
            for (int i = 0; i < 4; ++i)
                *(f16x8*)&lds[dbase + i * 1024 + lane * 16] = zf;
        }
    }
    __syncthreads();

    // ---------- K loop: 9 taps x 2 cin-halves, fully unrolled, 1-term f16
    const int wm = w >> 2;
    const int wn = w & 3;
    const int lm = lane & 15;
    const int lg = lane >> 4;

    f32x4 acc[4][4];
#pragma unroll
    for (int mf = 0; mf < 4; ++mf)
#pragma unroll
        for (int nf = 0; nf < 4; ++nf) acc[mf][nf] = (f32x4)0.0f;

    // per-lane swizzled A offsets: tx = lm + d, granule g = kk*4+lg, slot = g ^ (tx&7)
    unsigned av[3][2];
#pragma unroll
    for (int d = 0; d < 3; ++d)
#pragma unroll
        for (int kk = 0; kk < 2; ++kk) {
            const int tx = lm + d;
            av[d][kk] = (unsigned)(tx * 128 +
                        (((kk * 4 + lg) ^ (tx & 7)) << 4));
        }

    const f16x8* wb = (const f16x8*)wt + (size_t)(wn * 4) * 64 + lane;

    f16x8 bh[4];
#pragma unroll
    for (int it = 0; it < 18; ++it) {
        const int tap = it >> 1, kk = it & 1;
#pragma unroll
        for (int nf = 0; nf < 4; ++nf)
            bh[nf] = wb[(size_t)it * 1024 + nf * 64];
        const int ty = tap / 3;
        const int d  = tap - ty * 3;
        const unsigned abase = (unsigned)((wm + ty) * RS2) + av[d][kk];
        __builtin_amdgcn_s_setprio(1);
#pragma unroll
        for (int mf = 0; mf < 4; ++mf) {
            const f16x8 ah = *(const f16x8*)&lds[abase + mf * 2048];
#pragma unroll
            for (int nf = 0; nf < 4; ++nf)
                acc[mf][nf] = MFMA(ah, bh[nf], acc[mf][nf]);
        }
        __builtin_amdgcn_s_setprio(0);
    }

    __syncthreads();

    // ---------- epilogue: z-exchange through LDS, fused LSTM pointwise (c in f16)
    float* zbuf = (float*)lds;
    const int f = tid & 63;
    const float bi = bias[f], bfv = bias[64 + f], bcv = bias[128 + f], bov = bias[192 + f];

#pragma unroll 1
    for (int half = 0; half < 2; ++half) {
        if (wm == half) {
#pragma unroll
            for (int mf = 0; mf < 4; ++mf)
#pragma unroll
                for (int nf = 0; nf < 4; ++nf)
#pragma unroll
                    for (int j = 0; j < 4; ++j)
                        zbuf[(mf * 16 + lg * 4 + j) * ZS + wn * 64 + nf * 16 + lm] =
                            acc[mf][nf][j];
        }
        __syncthreads();
        const int gy = y0 + half;
#pragma unroll 1
        for (int k2 = 0; k2 < 8; ++k2) {
            const int x = (tid >> 6) + k2 * 8;          // 0..63 (wave-uniform)
            const float* zz = zbuf + x * ZS;
            float zi  = zz[f]       + bi;
            float zfv = zz[64 + f]  + bfv;
            float zc  = zz[128 + f] + bcv;
            float zo  = zz[192 + f] + bov;
            size_t goff = (((size_t)bb * NH + gy) * NW + x) * NF + f;
            float cp = (float)cbuf[goff];
            float ig = hsig(zi), fg = hsig(zfv), og = hsig(zo);
            float cn = fg * cp + ig * ftanh(zc);
            cbuf[goff] = (f16)cn;
            float hn = og * ftanh(cn);
            hout[(size_t)bb * OUT_BSTRIDE + (((size_t)gy * NW + x) * NF + f)] = hn;
            h2out[goff] = (f16)hn;
        }
        __syncthreads();
    }
}

extern "C" void kernel_launch(void* const* d_in, const int* in_sizes, int n_in,
                              void* d_out, int out_size, void* d_ws, size_t ws_size,
                              hipStream_t stream) {
    const float* h0    = (const float*)d_in[1];
    const float* c0    = (const float*)d_in[2];
    const float* kern  = (const float*)d_in[3];
    const float* rkern = (const float*)d_in[4];
    const float* bias  = (const float*)d_in[5];
    float* out = (float*)d_out;

    f16* wf2   = (f16*)d_ws;                                  // 4.7 MB (hi only)
    f16* h2a   = wf2 + (size_t)NT * WSTEP * 8;                // 8.4 MB
    f16* h2b   = h2a + (size_t)NB * HWF;                      // 8.4 MB
    f16* cbuf  = h2b + (size_t)NB * HWF;                      // 8.4 MB (f16 c state)

    const int n4 = (int)(NB * HWF / 4);                       // 1,048,576
    fuse_w_hi<<<(NT * 9 * NG * 8 + 255) / 256, 256, 0, stream>>>(kern, rkern, wf2);
    f32_to_f16<<<(n4 + 255) / 256, 256, 0, stream>>>(h0, h2a, n4);
    f32_to_f16<<<(n4 + 255) / 256, 256, 0, stream>>>(c0, cbuf, n4);

    for (int t = 0; t < NT; ++t) {
        const f16* hin = (t & 1) ? h2b : h2a;
        f16* hnx       = (t & 1) ? h2a : h2b;
        convlstm_mfma_step<<<dim3(512), 512, 0, stream>>>(
            hin, hnx, cbuf,
            out + (size_t)t * HWF,
            wf2 + (size_t)t * WSTEP * 8,
            bias + t * NG);
    }
}

// Round 14
// 384.340 us; speedup vs baseline: 1.9252x; 1.1552x over previous
//
#include <hip/hip_runtime.h>
#include <math.h>

typedef _Float16 f16;
typedef _Float16 f16x4 __attribute__((ext_vector_type(4)));
typedef _Float16 f16x8 __attribute__((ext_vector_type(8)));
typedef float f32x4 __attribute__((ext_vector_type(4)));

#define NB 16      // batch
#define NT 16      // time steps
#define NH 64
#define NW 64
#define NF 64      // features
#define NG 256     // 4*F
#define HWF ((size_t)NH * NW * NF)          // 262144
#define OUT_BSTRIDE ((size_t)NT * HWF)      // d_out batch stride
#define RS2 8448                            // LDS row stride = 66 * 128 B (x-padded)
#define WSTEP ((size_t)18432)               // per-step wf2 size in f16x8 chunks (hi-only)

#define MFMA(a, b, c) __builtin_amdgcn_mfma_f32_16x16x32_f16((a), (b), (c), 0, 0, 0)

__device__ __forceinline__ void gload_lds16(const void* g, void* l) {
    __builtin_amdgcn_global_load_lds(
        (const __attribute__((address_space(1))) unsigned int*)(g),
        (__attribute__((address_space(3))) unsigned int*)(l), 16, 0, 0);
}

__device__ __forceinline__ float hsig(float x) {
    return fminf(fmaxf(0.2f * x + 0.5f, 0.0f), 1.0f);
}

// fast tanh via v_exp_f32 (rounds 8-13 verified absmax-neutral)
__device__ __forceinline__ float ftanh(float x) {
    float t = __builtin_amdgcn_exp2f(x * 2.885390081777927f);
    return 1.0f - 2.0f * __builtin_amdgcn_rcpf(t + 1.0f);
}

// ---- prologue 1: fuse W+U -> f16 (hi only), lane-ordered, GATE-MAJOR blocks:
// chunk (f16x8 units): (tap*2+kk)*1024 + cb*64 + lane, with
// cb = ((cout>>4)&3)*4 + (cout>>6)   [f-group major, gate minor]
// lane = lg*16 + (cout&15) holds cin = kk*32 + lg*8 .. +7.
// => wave wn's 4 nf-fragments are gates i,f,c,o of features f = wn*16 + lm.
__global__ void fuse_w_hi(const float* __restrict__ k, const float* __restrict__ rk,
                          f16* __restrict__ wf2) {
    int idx = blockIdx.x * 256 + threadIdx.x;      // over 16*9*256*8 = 294912
    if (idx >= NT * 9 * NG * 8) return;
    int g8   = idx & 7;
    int cout = (idx >> 3) & 255;
    int tt   = idx >> 11;          // t*9 + tap
    int tap  = tt % 9;
    int t    = tt / 9;
    int kk = g8 >> 2, lg = g8 & 3;

    const float* ks = k  + (size_t)tt * NF * NG + cout;
    const float* rs = rk + (size_t)tt * NF * NG + cout;

    f16 hi8[8];
#pragma unroll
    for (int j = 0; j < 8; ++j) {
        int cin = kk * 32 + lg * 8 + j;
        hi8[j] = (f16)(ks[(size_t)cin * NG] + rs[(size_t)cin * NG]);
    }
    const int lane = lg * 16 + (cout & 15);
    const int cb   = ((cout >> 4) & 3) * 4 + (cout >> 6);   // gate-major permute
    size_t chunk = (size_t)t * WSTEP + (size_t)(tap * 2 + kk) * 1024 +
                   (size_t)cb * 64 + lane;
    *(f16x8*)&wf2[chunk * 8] = *(f16x8*)hi8;
}

// ---- prologue 2: f32 -> f16 vectorized converter (h0 and c0)
__global__ void f32_to_f16(const float* __restrict__ src, f16* __restrict__ dst, int n4) {
    int i = blockIdx.x * 256 + threadIdx.x;
    if (i >= n4) return;
    float4 v = ((const float4*)src)[i];
    f16x4 o = { (f16)v.x, (f16)v.y, (f16)v.z, (f16)v.w };
    *(f16x4*)&dst[(size_t)i * 4] = o;
}

// ---- one ConvLSTM step: 512 thr = 8 waves (2m x 4n), tile 128 pos x 256 couts.
// Gate-major B packing => each thread holds all 4 gates of its (pos, f) in acc
// => LSTM pointwise fully in-register: NO z-exchange, NO zbuf, ONE barrier/step.
// LDS = 33.8 KB (h tile only). Batch-sticky XCD decode (round 13).
__global__ void __launch_bounds__(512, 4)
convlstm_mfma_step(const f16* __restrict__ h2in, f16* __restrict__ h2out,
                   f16* __restrict__ cbuf,        // f16 cell state (in-place)
                   float* __restrict__ hout,        // d_out + t*HWF
                   const f16* __restrict__ wt,      // gate-major lane-ordered chunks
                   const float* __restrict__ bias)  // [256] for this t
{
    __shared__ __align__(16) unsigned char lds[4 * RS2];   // 33792 B

    const int tid  = threadIdx.x;
    const int w    = tid >> 6;
    const int lane = tid & 63;

    // batch-sticky XCD decode: id = xcd + 8*iy + 256*bhalf
    const int id = blockIdx.x;
    const int bb = ((id & 7) << 1) + ((id >> 8) & 1);
    const int y0 = ((id >> 3) & 31) * 2;

    const int wm = w >> 2;
    const int wn = w & 3;
    const int lm = lane & 15;
    const int lg = lane >> 4;

    // prefetch it=0 B fragments (independent of LDS staging)
    const f16x8* wb = (const f16x8*)wt + (size_t)(wn * 4) * 64 + lane;
    f16x8 bh[4];
#pragma unroll
    for (int nf = 0; nf < 4; ++nf)
        bh[nf] = wb[nf * 64];

    // zero the pad columns tx=0 and tx=65 (4 rows x 2 x 128B)
    if (tid < 64) {
        int row = tid >> 4, side = (tid >> 3) & 1, j = tid & 7;
        *(f16x8*)&lds[row * RS2 + side * (65 * 128) + j * 16] = (f16x8)(_Float16)0.0f;
    }

    // stage rows y0-1 .. y0+2 (f16, 128B per (y,x)); pre-swizzled global source
    {
        const int r    = w >> 1;               // tile row 0..3
        const int gy   = y0 - 1 + r;
        const int half = w & 1;
        const unsigned dbase = r * RS2 + 128 + half * 4096;  // wave-uniform
        if (gy >= 0 && gy < NH) {
            const unsigned char* gsrc = (const unsigned char*)h2in +
                ((((size_t)bb * NH + gy) * NW) << 7);        // 128 B per (y,x)
#pragma unroll
            for (int i = 0; i < 4; ++i) {
                const int xrel = half * 32 + i * 8 + (lane >> 3);
                const unsigned src = ((unsigned)xrel << 7) +
                    ((unsigned)((lane & 7) ^ ((xrel + 1) & 7)) << 4);
                gload_lds16(gsrc + src, (void*)&lds[dbase + i * 1024]);
            }
        } else {
            const f16x8 zf = (f16x8)(_Float16)0.0f;
#pragma unroll
            for (int i = 0; i < 4; ++i)
                *(f16x8*)&lds[dbase + i * 1024 + lane * 16] = zf;
        }
    }
    __syncthreads();        // the ONLY barrier in this kernel

    // ---------- K loop: 9 taps x 2 cin-halves, fully unrolled, 1-term f16
    f32x4 acc[4][4];
#pragma unroll
    for (int mf = 0; mf < 4; ++mf)
#pragma unroll
        for (int nf = 0; nf < 4; ++nf) acc[mf][nf] = (f32x4)0.0f;

    // per-lane swizzled A offsets: tx = lm + d, granule g = kk*4+lg, slot = g ^ (tx&7)
    unsigned av[3][2];
#pragma unroll
    for (int d = 0; d < 3; ++d)
#pragma unroll
        for (int kk = 0; kk < 2; ++kk) {
            const int tx = lm + d;
            av[d][kk] = (unsigned)(tx * 128 +
                        (((kk * 4 + lg) ^ (tx & 7)) << 4));
        }

#pragma unroll
    for (int it = 0; it < 18; ++it) {
        if (it > 0) {
#pragma unroll
            for (int nf = 0; nf < 4; ++nf)
                bh[nf] = wb[(size_t)it * 1024 + nf * 64];
        }
        const int tap = it >> 1, kk = it & 1;
        const int ty = tap / 3;
        const int d  = tap - ty * 3;
        const unsigned abase = (unsigned)((wm + ty) * RS2) + av[d][kk];
        __builtin_amdgcn_s_setprio(1);
#pragma unroll
        for (int mf = 0; mf < 4; ++mf) {
            const f16x8 ah = *(const f16x8*)&lds[abase + mf * 2048];
#pragma unroll
            for (int nf = 0; nf < 4; ++nf)
                acc[mf][nf] = MFMA(ah, bh[nf], acc[mf][nf]);
        }
        __builtin_amdgcn_s_setprio(0);
    }

    // ---------- epilogue: fully in-register LSTM pointwise (no LDS, no barrier)
    // acc[mf][gate][j] is z_gate at position x = mf*16 + lg*4 + j, feature f.
    const int f  = wn * 16 + lm;
    const int gy = y0 + wm;
    const float b0 = bias[f], b1 = bias[64 + f], b2 = bias[128 + f], b3 = bias[192 + f];

#pragma unroll
    for (int mf = 0; mf < 4; ++mf) {
        const int xb = mf * 16 + lg * 4;
        const size_t base = ((((size_t)bb * NH + gy) * NW + xb) << 6) + f;
        f16 cp4[4];
#pragma unroll
        for (int j = 0; j < 4; ++j)
            cp4[j] = cbuf[base + (size_t)j * 64];
#pragma unroll
        for (int j = 0; j < 4; ++j) {
            const float zi  = acc[mf][0][j] + b0;
            const float zfv = acc[mf][1][j] + b1;
            const float zc  = acc[mf][2][j] + b2;
            const float zo  = acc[mf][3][j] + b3;
            const float ig = hsig(zi), fg = hsig(zfv), og = hsig(zo);
            const float cn = fg * (float)cp4[j] + ig * ftanh(zc);
            cbuf[base + (size_t)j * 64] = (f16)cn;
            const float hn = og * ftanh(cn);
            hout[(size_t)bb * OUT_BSTRIDE + (((size_t)gy * NW + xb + j) << 6) + f] = hn;
            h2out[base + (size_t)j * 64] = (f16)hn;
        }
    }
}

extern "C" void kernel_launch(void* const* d_in, const int* in_sizes, int n_in,
                              void* d_out, int out_size, void* d_ws, size_t ws_size,
                              hipStream_t stream) {
    const float* h0    = (const float*)d_in[1];
    const float* c0    = (const float*)d_in[2];
    const float* kern  = (const float*)d_in[3];
    const float* rkern = (const float*)d_in[4];
    const float* bias  = (const float*)d_in[5];
    float* out = (float*)d_out;

    f16* wf2   = (f16*)d_ws;                                  // 4.7 MB (hi only)
    f16* h2a   = wf2 + (size_t)NT * WSTEP * 8;                // 8.4 MB
    f16* h2b   = h2a + (size_t)NB * HWF;                      // 8.4 MB
    f16* cbuf  = h2b + (size_t)NB * HWF;                      // 8.4 MB (f16 c state)

    const int n4 = (int)(NB * HWF / 4);                       // 1,048,576
    fuse_w_hi<<<(NT * 9 * NG * 8 + 255) / 256, 256, 0, stream>>>(kern, rkern, wf2);
    f32_to_f16<<<(n4 + 255) / 256, 256, 0, stream>>>(h0, h2a, n4);
    f32_to_f16<<<(n4 + 255) / 256, 256, 0, stream>>>(c0, cbuf, n4);

    for (int t = 0; t < NT; ++t) {
        const f16* hin = (t & 1) ? h2b : h2a;
        f16* hnx       = (t & 1) ? h2a : h2b;
        convlstm_mfma_step<<<dim3(512), 512, 0, stream>>>(
            hin, hnx, cbuf,
            out + (size_t)t * HWF,
            wf2 + (size_t)t * WSTEP * 8,
            bias + t * NG);
    }
}

// Round 15
// 378.769 us; speedup vs baseline: 1.9535x; 1.0147x over previous
//
#include <hip/hip_runtime.h>
#include <math.h>

typedef _Float16 f16;
typedef _Float16 f16x4 __attribute__((ext_vector_type(4)));
typedef _Float16 f16x8 __attribute__((ext_vector_type(8)));
typedef float f32x4 __attribute__((ext_vector_type(4)));

#define NB 16      // batch
#define NT 16      // time steps
#define NH 64
#define NW 64
#define NF 64      // features
#define NG 256     // 4*F
#define HWF ((size_t)NH * NW * NF)          // 262144
#define OUT_BSTRIDE ((size_t)NT * HWF)      // d_out batch stride
#define RS2 8448                            // LDS row stride = 66 * 128 B (x-padded)
#define WSTEP ((size_t)18432)               // per-step wf2 size in f16x8 chunks (hi-only)

#define MFMA(a, b, c) __builtin_amdgcn_mfma_f32_16x16x32_f16((a), (b), (c), 0, 0, 0)

__device__ __forceinline__ void gload_lds16(const void* g, void* l) {
    __builtin_amdgcn_global_load_lds(
        (const __attribute__((address_space(1))) unsigned int*)(g),
        (__attribute__((address_space(3))) unsigned int*)(l), 16, 0, 0);
}

__device__ __forceinline__ float hsig(float x) {
    return fminf(fmaxf(0.2f * x + 0.5f, 0.0f), 1.0f);
}

// fast tanh via v_exp_f32 (rounds 8-14 verified absmax-neutral)
__device__ __forceinline__ float ftanh(float x) {
    float t = __builtin_amdgcn_exp2f(x * 2.885390081777927f);
    return 1.0f - 2.0f * __builtin_amdgcn_rcpf(t + 1.0f);
}

// ---- prologue 1: fuse W+U -> f16 (hi only), lane-ordered, GATE-MAJOR blocks:
// chunk (f16x8 units): (tap*2+kk)*1024 + cb*64 + lane, with
// cb = ((cout>>4)&3)*4 + (cout>>6)   [f-group major, gate minor]
// lane = lg*16 + (cout&15) holds cin = kk*32 + lg*8 .. +7.
__global__ void fuse_w_hi(const float* __restrict__ k, const float* __restrict__ rk,
                          f16* __restrict__ wf2) {
    int idx = blockIdx.x * 256 + threadIdx.x;      // over 16*9*256*8 = 294912
    if (idx >= NT * 9 * NG * 8) return;
    int g8   = idx & 7;
    int cout = (idx >> 3) & 255;
    int tt   = idx >> 11;          // t*9 + tap
    int tap  = tt % 9;
    int t    = tt / 9;
    int kk = g8 >> 2, lg = g8 & 3;

    const float* ks = k  + (size_t)tt * NF * NG + cout;
    const float* rs = rk + (size_t)tt * NF * NG + cout;

    f16 hi8[8];
#pragma unroll
    for (int j = 0; j < 8; ++j) {
        int cin = kk * 32 + lg * 8 + j;
        hi8[j] = (f16)(ks[(size_t)cin * NG] + rs[(size_t)cin * NG]);
    }
    const int lane = lg * 16 + (cout & 15);
    const int cb   = ((cout >> 4) & 3) * 4 + (cout >> 6);   // gate-major permute
    size_t chunk = (size_t)t * WSTEP + (size_t)(tap * 2 + kk) * 1024 +
                   (size_t)cb * 64 + lane;
    *(f16x8*)&wf2[chunk * 8] = *(f16x8*)hi8;
}

// ---- prologue 2: f32 -> f16 vectorized converter (h0 and c0)
__global__ void f32_to_f16(const float* __restrict__ src, f16* __restrict__ dst, int n4) {
    int i = blockIdx.x * 256 + threadIdx.x;
    if (i >= n4) return;
    float4 v = ((const float4*)src)[i];
    f16x4 o = { (f16)v.x, (f16)v.y, (f16)v.z, (f16)v.w };
    *(f16x4*)&dst[(size_t)i * 4] = o;
}

// ---- one ConvLSTM step: 256 blocks (1/CU), 512 thr = 8 waves (2m x 4n).
// Block tile: 4 rows x 64 x x 256 couts. Each wave: M=128 (2 rows), N=64
// (4 gates x 16 f, gate-major) -> B-L2 traffic per CU HALVED vs round 14.
// acc = 128 VGPR; launch_bounds(512,2) caps at 256 VGPR (2 waves/SIMD).
// LDS: 6 staged rows (y0-1 .. y0+4), 50.7 KB. One barrier per step.
__global__ void __launch_bounds__(512, 2)
convlstm_mfma_step(const f16* __restrict__ h2in, f16* __restrict__ h2out,
                   f16* __restrict__ cbuf,        // f16 cell state (in-place)
                   float* __restrict__ hout,        // d_out + t*HWF
                   const f16* __restrict__ wt,      // gate-major lane-ordered chunks
                   const float* __restrict__ bias)  // [256] for this t
{
    __shared__ __align__(16) unsigned char lds[6 * RS2];   // 50688 B

    const int tid  = threadIdx.x;
    const int w    = tid >> 6;
    const int lane = tid & 63;

    // batch-sticky XCD decode: id = xcd + 8*iy + 128*bhalf ; 256 blocks total
    const int id = blockIdx.x;
    const int bb = ((id & 7) << 1) + ((id >> 7) & 1);
    const int y0 = ((id >> 3) & 15) * 4;

    const int wm = w >> 2;     // 0..1 : which row-pair of the 4-row tile
    const int wn = w & 3;      // 0..3 : feature group of 16
    const int lm = lane & 15;
    const int lg = lane >> 4;

    // prefetch it=0 B fragments (independent of staging)
    const f16x8* wb = (const f16x8*)wt + (size_t)(wn * 4) * 64 + lane;
    f16x8 bh[4];
#pragma unroll
    for (int nf = 0; nf < 4; ++nf)
        bh[nf] = wb[nf * 64];

    // prefetch c-state (independent of staging): 8 mf x 4 j scalar f16 loads
    const int f = wn * 16 + lm;
    f16 cp[8][4];
#pragma unroll
    for (int mf = 0; mf < 8; ++mf) {
        const int gy = y0 + wm * 2 + (mf >> 2);
        const int xb = (mf & 3) * 16 + lg * 4;
        const size_t base = ((((size_t)bb * NH + gy) * NW + xb) << 6) + f;
#pragma unroll
        for (int j = 0; j < 4; ++j)
            cp[mf][j] = cbuf[base + (size_t)j * 64];
    }

    // zero the pad columns tx=0 and tx=65 (6 rows x 2 x 8 granules)
    if (tid < 96) {
        int row = tid >> 4, side = (tid >> 3) & 1, j = tid & 7;
        *(f16x8*)&lds[row * RS2 + side * (65 * 128) + j * 16] = (f16x8)(_Float16)0.0f;
    }

    // stage rows y0-1 .. y0+4: wave w covers x in [w*8, w*8+8) for all 6 rows
    {
        const int x = w * 8 + (lane >> 3);
        const int g = lane & 7;
        const unsigned src = ((unsigned)x << 7) +
                             ((unsigned)(g ^ ((x + 1) & 7)) << 4);
#pragma unroll
        for (int k = 0; k < 6; ++k) {
            const int gy = y0 - 1 + k;
            const unsigned dbase = k * RS2 + 128 + w * 1024;   // wave-uniform
            if (gy >= 0 && gy < NH) {
                const unsigned char* gsrc = (const unsigned char*)h2in +
                    ((((size_t)bb * NH + gy) * NW) << 7);
                gload_lds16(gsrc + src, (void*)&lds[dbase]);
            } else {
                *(f16x8*)&lds[dbase + lane * 16] = (f16x8)(_Float16)0.0f;
            }
        }
    }
    __syncthreads();        // the ONLY barrier

    // ---------- K loop: 9 taps x 2 cin-halves, fully unrolled, 1-term f16
    f32x4 acc[8][4];
#pragma unroll
    for (int mf = 0; mf < 8; ++mf)
#pragma unroll
        for (int nf = 0; nf < 4; ++nf) acc[mf][nf] = (f32x4)0.0f;

    // per-lane swizzled A offsets: tx = lm + d, granule g = kk*4+lg, slot = g ^ (tx&7)
    unsigned av[3][2];
#pragma unroll
    for (int d = 0; d < 3; ++d)
#pragma unroll
        for (int kk = 0; kk < 2; ++kk) {
            const int tx = lm + d;
            av[d][kk] = (unsigned)(tx * 128 +
                        (((kk * 4 + lg) ^ (tx & 7)) << 4));
        }

#pragma unroll
    for (int it = 0; it < 18; ++it) {
        if (it > 0) {
#pragma unroll
            for (int nf = 0; nf < 4; ++nf)
                bh[nf] = wb[(size_t)it * 1024 + nf * 64];
        }
        const int tap = it >> 1, kk = it & 1;
        const int ty = tap / 3;
        const int d  = tap - ty * 3;
        const unsigned abase = (unsigned)((wm * 2 + ty) * RS2) + av[d][kk];
        __builtin_amdgcn_s_setprio(1);
#pragma unroll
        for (int mf = 0; mf < 8; ++mf) {
            // A row = wm*2 + (mf>>2) + ty ; x-block = mf&3
            const f16x8 ah = *(const f16x8*)&lds[abase + (mf >> 2) * RS2 +
                                                 (mf & 3) * 2048];
#pragma unroll
            for (int nf = 0; nf < 4; ++nf)
                acc[mf][nf] = MFMA(ah, bh[nf], acc[mf][nf]);
        }
        __builtin_amdgcn_s_setprio(0);
    }

    // ---------- epilogue: fully in-register LSTM pointwise
    const float b0 = bias[f], b1 = bias[64 + f], b2 = bias[128 + f], b3 = bias[192 + f];

#pragma unroll
    for (int mf = 0; mf < 8; ++mf) {
        const int gy = y0 + wm * 2 + (mf >> 2);
        const int xb = (mf & 3) * 16 + lg * 4;
        const size_t base = ((((size_t)bb * NH + gy) * NW + xb) << 6) + f;
#pragma unroll
        for (int j = 0; j < 4; ++j) {
            const float zi  = acc[mf][0][j] + b0;
            const float zfv = acc[mf][1][j] + b1;
            const float zc  = acc[mf][2][j] + b2;
            const float zo  = acc[mf][3][j] + b3;
            const float ig = hsig(zi), fg = hsig(zfv), og = hsig(zo);
            const float cn = fg * (float)cp[mf][j] + ig * ftanh(zc);
            cbuf[base + (size_t)j * 64] = (f16)cn;
            const float hn = og * ftanh(cn);
            hout[(size_t)bb * OUT_BSTRIDE + (((size_t)gy * NW + xb + j) << 6) + f] = hn;
            h2out[base + (size_t)j * 64] = (f16)hn;
        }
    }
}

extern "C" void kernel_launch(void* const* d_in, const int* in_sizes, int n_in,
                              void* d_out, int out_size, void* d_ws, size_t ws_size,
                              hipStream_t stream) {
    const float* h0    = (const float*)d_in[1];
    const float* c0    = (const float*)d_in[2];
    const float* kern  = (const float*)d_in[3];
    const float* rkern = (const float*)d_in[4];
    const float* bias  = (const float*)d_in[5];
    float* out = (float*)d_out;

    f16* wf2   = (f16*)d_ws;                                  // 4.7 MB (hi only)
    f16* h2a   = wf2 + (size_t)NT * WSTEP * 8;                // 8.4 MB
    f16* h2b   = h2a + (size_t)NB * HWF;                      // 8.4 MB
    f16* cbuf  = h2b + (size_t)NB * HWF;                      // 8.4 MB (f16 c state)

    const int n4 = (int)(NB * HWF / 4);                       // 1,048,576
    fuse_w_hi<<<(NT * 9 * NG * 8 + 255) / 256, 256, 0, stream>>>(kern, rkern, wf2);
    f32_to_f16<<<(n4 + 255) / 256, 256, 0, stream>>>(h0, h2a, n4);
    f32_to_f16<<<(n4 + 255) / 256, 256, 0, stream>>>(c0, cbuf, n4);

    for (int t = 0; t < NT; ++t) {
        const f16* hin = (t & 1) ? h2b : h2a;
        f16* hnx       = (t & 1) ? h2a : h2b;
        convlstm_mfma_step<<<dim3(256), 512, 0, stream>>>(
            hin, hnx, cbuf,
            out + (size_t)t * HWF,
            wf2 + (size_t)t * WSTEP * 8,
            bias + t * NG);
    }
}